// Round 1
// baseline (761.498 us; speedup 1.0000x reference)
//
#include <hip/hip_runtime.h>
#include <hip/hip_bf16.h>

#define S_LEN 2048
#define DIM_  2048
#define NH    32
#define NKV   8
#define HD    64
#define SCALE 0.125f   // HD^-0.5

typedef __bf16 bf16x8 __attribute__((ext_vector_type(8)));
typedef float  f32x4  __attribute__((ext_vector_type(4)));

__device__ inline bf16x8 load_cvt8(const float* __restrict__ p) {
  float4 f0 = *(const float4*)(p);
  float4 f1 = *(const float4*)(p + 4);
  bf16x8 r;
  r[0] = (__bf16)f0.x; r[1] = (__bf16)f0.y; r[2] = (__bf16)f0.z; r[3] = (__bf16)f0.w;
  r[4] = (__bf16)f1.x; r[5] = (__bf16)f1.y; r[6] = (__bf16)f1.z; r[7] = (__bf16)f1.w;
  return r;
}

// ---------------- QKV projection: C[M=2048][N=3072] = x @ [wq;wk;wv]^T ------
// Block: 256 thr (4 waves, 2x2), computes 64x64 tile. Grid: (48, 32).
// Q -> [NH][S][HD], K -> [NKV][S][HD], V -> transposed [NKV][HD][S].
__global__ __launch_bounds__(256) void qkv_kernel(
    const float* __restrict__ x,  const float* __restrict__ wq,
    const float* __restrict__ wk, const float* __restrict__ wv,
    __bf16* __restrict__ q_buf, __bf16* __restrict__ k_buf, __bf16* __restrict__ v_buf)
{
  const int lane = threadIdx.x & 63;
  const int wave = threadIdx.x >> 6;
  const int wr = wave >> 1, wc = wave & 1;
  const int row0 = blockIdx.y * 64 + wr * 32;
  const int bx = blockIdx.x;
  const int col0 = bx * 64 + wc * 32;
  const int lrow = lane & 15;
  const int lgrp = lane >> 4;
  const int lk = lgrp * 8;

  const float* wbase; int noff;
  if (bx < 32)      { wbase = wq; noff = 0; }
  else if (bx < 40) { wbase = wk; noff = 2048; }
  else              { wbase = wv; noff = 2560; }

  f32x4 acc[2][2] = {};

  for (int k0 = 0; k0 < DIM_; k0 += 32) {
    bf16x8 a[2], b[2];
#pragma unroll
    for (int mi = 0; mi < 2; ++mi)
      a[mi] = load_cvt8(x + (size_t)(row0 + mi * 16 + lrow) * DIM_ + k0 + lk);
#pragma unroll
    for (int ni = 0; ni < 2; ++ni)
      b[ni] = load_cvt8(wbase + (size_t)(col0 - noff + ni * 16 + lrow) * DIM_ + k0 + lk);
#pragma unroll
    for (int mi = 0; mi < 2; ++mi)
#pragma unroll
      for (int ni = 0; ni < 2; ++ni)
        acc[mi][ni] = __builtin_amdgcn_mfma_f32_16x16x32_bf16(a[mi], b[ni], acc[mi][ni], 0, 0, 0);
  }

#pragma unroll
  for (int mi = 0; mi < 2; ++mi) {
#pragma unroll
    for (int ni = 0; ni < 2; ++ni) {
#pragma unroll
      for (int j = 0; j < 4; ++j) {
        int row = row0 + mi * 16 + lgrp * 4 + j;
        int col = col0 + ni * 16 + lrow;
        float v = acc[mi][ni][j];
        if (col < 2048) {
          int h = col >> 6, d = col & 63;
          q_buf[((size_t)h * S_LEN + row) * HD + d] = (__bf16)v;
        } else if (col < 2560) {
          int c = col - 2048, g = c >> 6, d = c & 63;
          k_buf[((size_t)g * S_LEN + row) * HD + d] = (__bf16)v;
        } else {
          int c = col - 2560, g = c >> 6, d = c & 63;
          v_buf[((size_t)g * HD + d) * S_LEN + row] = (__bf16)v;  // transposed
        }
      }
    }
  }
}

// ---------------- RoPE on Q and K (in place, bf16) --------------------------
__global__ __launch_bounds__(256) void rope_kernel(
    __bf16* __restrict__ q_buf, __bf16* __restrict__ k_buf,
    const float* __restrict__ fc)
{
  int idx = blockIdx.x * 256 + threadIdx.x;  // (NH+NKV)*S*32 threads exactly
  int i    = idx & 31;        // d-pair index (HD/2 = 32)
  int hs   = idx >> 5;
  int spos = hs & (S_LEN - 1);
  int h    = hs >> 11;        // S_LEN = 2048
  __bf16* buf = (h < NH) ? (q_buf + ((size_t)h * S_LEN + spos) * HD)
                         : (k_buf + ((size_t)(h - NH) * S_LEN + spos) * HD);
  float c = fc[(spos * 32 + i) * 2 + 0];
  float s = fc[(spos * 32 + i) * 2 + 1];
  float x1 = (float)buf[2 * i], x2 = (float)buf[2 * i + 1];
  buf[2 * i + 0] = (__bf16)(x1 * c - x2 * s);
  buf[2 * i + 1] = (__bf16)(x1 * s + x2 * c);
}

// ---------------- Flash attention (causal, GQA) -----------------------------
// Grid: (S/64, NH). Block: 4 waves; wave w owns q-rows [qt*64+w*16, +16).
__global__ __launch_bounds__(256) void attn_kernel(
    const __bf16* __restrict__ q_buf, const __bf16* __restrict__ k_buf,
    const __bf16* __restrict__ v_buf, __bf16* __restrict__ attn_buf)
{
  __shared__ __bf16 lds_p[4][16][40];  // per-wave P tile, padded
  const int lane = threadIdx.x & 63;
  const int wave = threadIdx.x >> 6;
  const int qt = blockIdx.x;
  const int h  = blockIdx.y;
  const int g  = h >> 2;             // NREP = 4
  const int r0 = qt * 64 + wave * 16;
  const int lrow = lane & 15;
  const int lgrp = lane >> 4;
  const int lk = lgrp * 8;

  const __bf16* qh = q_buf + (size_t)h * S_LEN * HD;
  const __bf16* kh = k_buf + (size_t)g * S_LEN * HD;
  const __bf16* vh = v_buf + (size_t)g * HD * S_LEN;

  bf16x8 qa[2];
#pragma unroll
  for (int kk = 0; kk < 2; ++kk)
    qa[kk] = *(const bf16x8*)(qh + (size_t)(r0 + lrow) * HD + kk * 32 + lk);

  float m[4], lsum[4];
  f32x4 oacc[4] = {};
#pragma unroll
  for (int j = 0; j < 4; ++j) { m[j] = -1e30f; lsum[j] = 0.f; }

  const int ntiles = qt * 2 + 2;
  for (int t = 0; t < ntiles; ++t) {
    const int t0 = t * 32;
    f32x4 sacc[2] = {};
#pragma unroll
    for (int ni = 0; ni < 2; ++ni) {
#pragma unroll
      for (int kk = 0; kk < 2; ++kk) {
        bf16x8 kb = *(const bf16x8*)(kh + (size_t)(t0 + ni * 16 + lrow) * HD + kk * 32 + lk);
        sacc[ni] = __builtin_amdgcn_mfma_f32_16x16x32_bf16(qa[kk], kb, sacc[ni], 0, 0, 0);
      }
    }
    float pm[4], p0[4], p1[4];
#pragma unroll
    for (int j = 0; j < 4; ++j) {
      int row = r0 + lgrp * 4 + j;
      float s0 = sacc[0][j] * SCALE;
      float s1 = sacc[1][j] * SCALE;
      if (t0 + lrow > row)      s0 = -1e30f;
      if (t0 + 16 + lrow > row) s1 = -1e30f;
      p0[j] = s0; p1[j] = s1;
      pm[j] = fmaxf(s0, s1);
    }
#pragma unroll
    for (int msk = 1; msk < 16; msk <<= 1)
#pragma unroll
      for (int j = 0; j < 4; ++j)
        pm[j] = fmaxf(pm[j], __shfl_xor(pm[j], msk, 64));

    float alpha[4];
#pragma unroll
    for (int j = 0; j < 4; ++j) {
      float nm = fmaxf(m[j], pm[j]);
      alpha[j] = expf(m[j] - nm);
      m[j] = nm;
      float e0 = expf(p0[j] - nm);
      float e1 = expf(p1[j] - nm);
      float rs = e0 + e1;
#pragma unroll
      for (int msk = 1; msk < 16; msk <<= 1)
        rs += __shfl_xor(rs, msk, 64);
      lsum[j] = lsum[j] * alpha[j] + rs;
      lds_p[wave][lgrp * 4 + j][lrow]      = (__bf16)e0;
      lds_p[wave][lgrp * 4 + j][16 + lrow] = (__bf16)e1;
    }
#pragma unroll
    for (int nf = 0; nf < 4; ++nf)
#pragma unroll
      for (int j = 0; j < 4; ++j)
        oacc[nf][j] *= alpha[j];

    __syncthreads();
    bf16x8 pa = *(const bf16x8*)&lds_p[wave][lrow][lk];
#pragma unroll
    for (int nf = 0; nf < 4; ++nf) {
      bf16x8 vb = *(const bf16x8*)(vh + (size_t)(nf * 16 + lrow) * S_LEN + t0 + lk);
      oacc[nf] = __builtin_amdgcn_mfma_f32_16x16x32_bf16(pa, vb, oacc[nf], 0, 0, 0);
    }
    __syncthreads();
  }

#pragma unroll
  for (int nf = 0; nf < 4; ++nf) {
#pragma unroll
    for (int j = 0; j < 4; ++j) {
      int row = r0 + lgrp * 4 + j;
      float v = oacc[nf][j] / lsum[j];
      attn_buf[(size_t)row * (NH * HD) + h * HD + nf * 16 + lrow] = (__bf16)v;
    }
  }
}

// ---------------- Output projection: out = attn @ wo^T ----------------------
__global__ __launch_bounds__(256) void oproj_kernel(
    const __bf16* __restrict__ attn_buf, const float* __restrict__ wo,
    float* __restrict__ out)
{
  const int lane = threadIdx.x & 63;
  const int wave = threadIdx.x >> 6;
  const int wr = wave >> 1, wc = wave & 1;
  const int row0 = blockIdx.y * 64 + wr * 32;
  const int col0 = blockIdx.x * 64 + wc * 32;
  const int lrow = lane & 15;
  const int lgrp = lane >> 4;
  const int lk = lgrp * 8;

  f32x4 acc[2][2] = {};
  for (int k0 = 0; k0 < DIM_; k0 += 32) {
    bf16x8 a[2], b[2];
#pragma unroll
    for (int mi = 0; mi < 2; ++mi)
      a[mi] = *(const bf16x8*)(attn_buf + (size_t)(row0 + mi * 16 + lrow) * DIM_ + k0 + lk);
#pragma unroll
    for (int ni = 0; ni < 2; ++ni)
      b[ni] = load_cvt8(wo + (size_t)(col0 + ni * 16 + lrow) * DIM_ + k0 + lk);
#pragma unroll
    for (int mi = 0; mi < 2; ++mi)
#pragma unroll
      for (int ni = 0; ni < 2; ++ni)
        acc[mi][ni] = __builtin_amdgcn_mfma_f32_16x16x32_bf16(a[mi], b[ni], acc[mi][ni], 0, 0, 0);
  }

#pragma unroll
  for (int mi = 0; mi < 2; ++mi)
#pragma unroll
    for (int ni = 0; ni < 2; ++ni)
#pragma unroll
      for (int j = 0; j < 4; ++j) {
        int row = row0 + mi * 16 + lgrp * 4 + j;
        int col = col0 + ni * 16 + lrow;
        out[(size_t)row * DIM_ + col] = acc[mi][ni][j];
      }
}

extern "C" void kernel_launch(void* const* d_in, const int* in_sizes, int n_in,
                              void* d_out, int out_size, void* d_ws, size_t ws_size,
                              hipStream_t stream)
{
  const float* x  = (const float*)d_in[0];
  const float* wq = (const float*)d_in[1];
  const float* wk = (const float*)d_in[2];
  const float* wv = (const float*)d_in[3];
  const float* wo = (const float*)d_in[4];
  const float* fc = (const float*)d_in[5];
  // d_in[6] = mask: causal triu(-1e9) applied analytically inside attn_kernel.
  float* out = (float*)d_out;

  char* ws = (char*)d_ws;
  __bf16* q_buf    = (__bf16*)(ws);                       // 8 MB  [NH][S][HD]
  __bf16* k_buf    = (__bf16*)(ws + 8u * 1024 * 1024);    // 2 MB  [NKV][S][HD]
  __bf16* v_buf    = (__bf16*)(ws + 10u * 1024 * 1024);   // 2 MB  [NKV][HD][S]
  __bf16* attn_buf = (__bf16*)(ws + 12u * 1024 * 1024);   // 8 MB  [S][NH*HD]

  qkv_kernel<<<dim3(48, 32), 256, 0, stream>>>(x, wq, wk, wv, q_buf, k_buf, v_buf);
  rope_kernel<<<dim3(10240), 256, 0, stream>>>(q_buf, k_buf, fc);
  attn_kernel<<<dim3(32, 32), 256, 0, stream>>>(q_buf, k_buf, v_buf, attn_buf);
  oproj_kernel<<<dim3(32, 32), 256, 0, stream>>>(attn_buf, wo, out);
}

// Round 2
// 374.705 us; speedup vs baseline: 2.0323x; 2.0323x over previous
//
#include <hip/hip_runtime.h>
#include <hip/hip_bf16.h>

#define S_LEN 2048
#define DIM_  2048
#define NH    32
#define NKV   8
#define HD    64
#define SCALE 0.125f   // HD^-0.5

typedef __bf16 bf16x8 __attribute__((ext_vector_type(8)));
typedef __bf16 bf16x4 __attribute__((ext_vector_type(4)));
typedef float  f32x4  __attribute__((ext_vector_type(4)));

#define AS_GLOBAL(p) ((const __attribute__((address_space(1))) void*)(p))
#define AS_LDS(p)    ((__attribute__((address_space(3))) void*)(p))

// ---------------- fp32 -> bf16 conversion (x, wq|wk|wv concat, wo) ----------
// One float4 per thread. Segments (in float4 units):
//   x: [0, 1048576)  wq: [.., +1048576)  wk: +262144  wv: +262144  wo: +1048576
__global__ __launch_bounds__(256) void cvt_kernel(
    const float* __restrict__ x,  const float* __restrict__ wq,
    const float* __restrict__ wk, const float* __restrict__ wv,
    const float* __restrict__ wo,
    __bf16* __restrict__ xb, __bf16* __restrict__ wb, __bf16* __restrict__ wob)
{
  size_t i = (size_t)blockIdx.x * 256 + threadIdx.x;
  const float* src; __bf16* dst; size_t off;
  if (i < 1048576)      { src = x;  dst = xb;            off = i; }
  else if (i < 2097152) { src = wq; dst = wb;            off = i - 1048576; }
  else if (i < 2359296) { src = wk; dst = wb + 4194304;  off = i - 2097152; }
  else if (i < 2621440) { src = wv; dst = wb + 5242880;  off = i - 2359296; }
  else                  { src = wo; dst = wob;           off = i - 2621440; }
  float4 f = ((const float4*)src)[off];
  bf16x4 r;
  r[0] = (__bf16)f.x; r[1] = (__bf16)f.y; r[2] = (__bf16)f.z; r[3] = (__bf16)f.w;
  ((bf16x4*)dst)[off] = r;
}

// ---------------- m97-structure GEMM main loop ------------------------------
// C[128][128] tile = A[128][K] @ B[128][K]^T (both bf16, K-contiguous).
// 4 waves (2x2), each computes 64x64 = 4x4 frags of 16x16x32 MFMA.
// LDS: double-buffered 128x32 bf16 tiles (8 KB each), staged via
// global_load_lds width-16 (wave-uniform LDS base + lane*16).
#define BK 32
#define TILE_ELEMS 4096   // 128*32

__device__ __forceinline__ void stage_tile(
    const __bf16* __restrict__ g, int row0, int k0, int ld,
    __bf16* lds, int wave, int lane)
{
#pragma unroll
  for (int iss = 0; iss < 2; ++iss) {
    int off = (wave * 2 + iss) * 1024 + lane * 16;  // byte offset in 8 KB tile
    int r = off >> 6;          // 64 B per row (32 bf16)
    int c = (off & 63) >> 1;   // bf16 col
    __builtin_amdgcn_global_load_lds(
        AS_GLOBAL(g + (size_t)(row0 + r) * ld + k0 + c),
        AS_LDS(lds + (wave * 2 + iss) * 512),   // wave-uniform base
        16, 0, 0);
  }
}

__device__ __forceinline__ void gemm_mainloop(
    const __bf16* __restrict__ A, const __bf16* __restrict__ B,
    int row0, int col0, int lda, int ldb, int nt,
    __bf16* As, __bf16* Bs, f32x4 acc[4][4])
{
  const int lane = threadIdx.x & 63;
  const int wave = threadIdx.x >> 6;
  const int wr = wave >> 1, wc = wave & 1;
  const int fr = lane & 15, fg = lane >> 4;

  stage_tile(A, row0, 0, lda, As, wave, lane);
  stage_tile(B, col0, 0, ldb, Bs, wave, lane);

  for (int t = 0; t < nt; ++t) {
    const int cur = t & 1;
    if (t + 1 < nt) {
      stage_tile(A, row0, (t + 1) * BK, lda, As + (cur ^ 1) * TILE_ELEMS, wave, lane);
      stage_tile(B, col0, (t + 1) * BK, ldb, Bs + (cur ^ 1) * TILE_ELEMS, wave, lane);
    }
    __syncthreads();   // drains vmcnt -> buf[cur] ready
    bf16x8 a[4], b[4];
#pragma unroll
    for (int mi = 0; mi < 4; ++mi)
      a[mi] = *(const bf16x8*)(As + cur * TILE_ELEMS + (wr * 64 + mi * 16 + fr) * 32 + fg * 8);
#pragma unroll
    for (int ni = 0; ni < 4; ++ni)
      b[ni] = *(const bf16x8*)(Bs + cur * TILE_ELEMS + (wc * 64 + ni * 16 + fr) * 32 + fg * 8);
#pragma unroll
    for (int mi = 0; mi < 4; ++mi)
#pragma unroll
      for (int ni = 0; ni < 4; ++ni)
        acc[mi][ni] = __builtin_amdgcn_mfma_f32_16x16x32_bf16(a[mi], b[ni], acc[mi][ni], 0, 0, 0);
    __syncthreads();   // all waves done reading buf[cur] before next stage overwrites
  }
}

// ---------------- QKV projection ------------------------------------------
// Grid (24, 16): 128-col x 128-row tiles over C[2048][3072].
// Scatter: Q -> [NH][S][HD], K -> [NKV][S][HD], V -> transposed [NKV][HD][S].
__global__ __launch_bounds__(256) void qkv_gemm(
    const __bf16* __restrict__ xb, const __bf16* __restrict__ wb,
    __bf16* __restrict__ q_buf, __bf16* __restrict__ k_buf, __bf16* __restrict__ v_buf)
{
  __shared__ __bf16 As[2 * TILE_ELEMS];
  __shared__ __bf16 Bs[2 * TILE_ELEMS];
  const int lane = threadIdx.x & 63;
  const int wave = threadIdx.x >> 6;
  const int wr = wave >> 1, wc = wave & 1;
  const int fr = lane & 15, fg = lane >> 4;
  const int row0 = blockIdx.y * 128;
  const int col0 = blockIdx.x * 128;

  f32x4 acc[4][4] = {};
  gemm_mainloop(xb, wb, row0, col0, DIM_, DIM_, DIM_ / BK, As, Bs, acc);

  const int rowg0 = row0 + wr * 64;
  const int colg0 = col0 + wc * 64;
#pragma unroll
  for (int mi = 0; mi < 4; ++mi) {
#pragma unroll
    for (int ni = 0; ni < 4; ++ni) {
#pragma unroll
      for (int j = 0; j < 4; ++j) {
        int row = rowg0 + mi * 16 + fg * 4 + j;
        int col = colg0 + ni * 16 + fr;
        float v = acc[mi][ni][j];
        if (col < 2048) {
          int h = col >> 6, d = col & 63;
          q_buf[((size_t)h * S_LEN + row) * HD + d] = (__bf16)v;
        } else if (col < 2560) {
          int c = col - 2048, g = c >> 6, d = c & 63;
          k_buf[((size_t)g * S_LEN + row) * HD + d] = (__bf16)v;
        } else {
          int c = col - 2560, g = c >> 6, d = c & 63;
          v_buf[((size_t)g * HD + d) * S_LEN + row] = (__bf16)v;  // transposed
        }
      }
    }
  }
}

// ---------------- Output projection: out = attn @ wo^T ----------------------
__global__ __launch_bounds__(256) void oproj_gemm(
    const __bf16* __restrict__ attn_buf, const __bf16* __restrict__ wob,
    float* __restrict__ out)
{
  __shared__ __bf16 As[2 * TILE_ELEMS];
  __shared__ __bf16 Bs[2 * TILE_ELEMS];
  const int lane = threadIdx.x & 63;
  const int wave = threadIdx.x >> 6;
  const int wr = wave >> 1, wc = wave & 1;
  const int fr = lane & 15, fg = lane >> 4;
  const int row0 = blockIdx.y * 128;
  const int col0 = blockIdx.x * 128;

  f32x4 acc[4][4] = {};
  gemm_mainloop(attn_buf, wob, row0, col0, DIM_, DIM_, DIM_ / BK, As, Bs, acc);

  const int rowg0 = row0 + wr * 64;
  const int colg0 = col0 + wc * 64;
#pragma unroll
  for (int mi = 0; mi < 4; ++mi)
#pragma unroll
    for (int ni = 0; ni < 4; ++ni)
#pragma unroll
      for (int j = 0; j < 4; ++j) {
        int row = rowg0 + mi * 16 + fg * 4 + j;
        int col = colg0 + ni * 16 + fr;
        out[(size_t)row * DIM_ + col] = acc[mi][ni][j];
      }
}

// ---------------- RoPE on Q and K (in place, bf16) --------------------------
__global__ __launch_bounds__(256) void rope_kernel(
    __bf16* __restrict__ q_buf, __bf16* __restrict__ k_buf,
    const float* __restrict__ fc)
{
  int idx = blockIdx.x * 256 + threadIdx.x;  // (NH+NKV)*S*32 threads exactly
  int i    = idx & 31;        // d-pair index (HD/2 = 32)
  int hs   = idx >> 5;
  int spos = hs & (S_LEN - 1);
  int h    = hs >> 11;        // S_LEN = 2048
  __bf16* buf = (h < NH) ? (q_buf + ((size_t)h * S_LEN + spos) * HD)
                         : (k_buf + ((size_t)(h - NH) * S_LEN + spos) * HD);
  float c = fc[(spos * 32 + i) * 2 + 0];
  float s = fc[(spos * 32 + i) * 2 + 1];
  float x1 = (float)buf[2 * i], x2 = (float)buf[2 * i + 1];
  buf[2 * i + 0] = (__bf16)(x1 * c - x2 * s);
  buf[2 * i + 1] = (__bf16)(x1 * s + x2 * c);
}

// ---------------- Flash attention (causal, GQA) -----------------------------
// Grid: (S/64, NH). Block: 4 waves; wave w owns q-rows [qt*64+w*16, +16).
__global__ __launch_bounds__(256) void attn_kernel(
    const __bf16* __restrict__ q_buf, const __bf16* __restrict__ k_buf,
    const __bf16* __restrict__ v_buf, __bf16* __restrict__ attn_buf)
{
  __shared__ __bf16 lds_p[4][16][40];  // per-wave P tile, padded
  const int lane = threadIdx.x & 63;
  const int wave = threadIdx.x >> 6;
  const int qt = blockIdx.x;
  const int h  = blockIdx.y;
  const int g  = h >> 2;             // NREP = 4
  const int r0 = qt * 64 + wave * 16;
  const int lrow = lane & 15;
  const int lgrp = lane >> 4;
  const int lk = lgrp * 8;

  const __bf16* qh = q_buf + (size_t)h * S_LEN * HD;
  const __bf16* kh = k_buf + (size_t)g * S_LEN * HD;
  const __bf16* vh = v_buf + (size_t)g * HD * S_LEN;

  bf16x8 qa[2];
#pragma unroll
  for (int kk = 0; kk < 2; ++kk)
    qa[kk] = *(const bf16x8*)(qh + (size_t)(r0 + lrow) * HD + kk * 32 + lk);

  float m[4], lsum[4];
  f32x4 oacc[4] = {};
#pragma unroll
  for (int j = 0; j < 4; ++j) { m[j] = -1e30f; lsum[j] = 0.f; }

  const int ntiles = qt * 2 + 2;
  for (int t = 0; t < ntiles; ++t) {
    const int t0 = t * 32;
    f32x4 sacc[2] = {};
#pragma unroll
    for (int ni = 0; ni < 2; ++ni) {
#pragma unroll
      for (int kk = 0; kk < 2; ++kk) {
        bf16x8 kb = *(const bf16x8*)(kh + (size_t)(t0 + ni * 16 + lrow) * HD + kk * 32 + lk);
        sacc[ni] = __builtin_amdgcn_mfma_f32_16x16x32_bf16(qa[kk], kb, sacc[ni], 0, 0, 0);
      }
    }
    float pm[4], p0[4], p1[4];
#pragma unroll
    for (int j = 0; j < 4; ++j) {
      int row = r0 + lgrp * 4 + j;
      float s0 = sacc[0][j] * SCALE;
      float s1 = sacc[1][j] * SCALE;
      if (t0 + lrow > row)      s0 = -1e30f;
      if (t0 + 16 + lrow > row) s1 = -1e30f;
      p0[j] = s0; p1[j] = s1;
      pm[j] = fmaxf(s0, s1);
    }
#pragma unroll
    for (int msk = 1; msk < 16; msk <<= 1)
#pragma unroll
      for (int j = 0; j < 4; ++j)
        pm[j] = fmaxf(pm[j], __shfl_xor(pm[j], msk, 64));

    float alpha[4];
#pragma unroll
    for (int j = 0; j < 4; ++j) {
      float nm = fmaxf(m[j], pm[j]);
      alpha[j] = expf(m[j] - nm);
      m[j] = nm;
      float e0 = expf(p0[j] - nm);
      float e1 = expf(p1[j] - nm);
      float rs = e0 + e1;
#pragma unroll
      for (int msk = 1; msk < 16; msk <<= 1)
        rs += __shfl_xor(rs, msk, 64);
      lsum[j] = lsum[j] * alpha[j] + rs;
      lds_p[wave][lgrp * 4 + j][lrow]      = (__bf16)e0;
      lds_p[wave][lgrp * 4 + j][16 + lrow] = (__bf16)e1;
    }
#pragma unroll
    for (int nf = 0; nf < 4; ++nf)
#pragma unroll
      for (int j = 0; j < 4; ++j)
        oacc[nf][j] *= alpha[j];

    __syncthreads();
    bf16x8 pa = *(const bf16x8*)&lds_p[wave][lrow][lk];
#pragma unroll
    for (int nf = 0; nf < 4; ++nf) {
      bf16x8 vb = *(const bf16x8*)(vh + (size_t)(nf * 16 + lrow) * S_LEN + t0 + lk);
      oacc[nf] = __builtin_amdgcn_mfma_f32_16x16x32_bf16(pa, vb, oacc[nf], 0, 0, 0);
    }
    __syncthreads();
  }

#pragma unroll
  for (int nf = 0; nf < 4; ++nf) {
#pragma unroll
    for (int j = 0; j < 4; ++j) {
      int row = r0 + lgrp * 4 + j;
      float v = oacc[nf][j] / lsum[j];
      attn_buf[(size_t)row * (NH * HD) + h * HD + nf * 16 + lrow] = (__bf16)v;
    }
  }
}

extern "C" void kernel_launch(void* const* d_in, const int* in_sizes, int n_in,
                              void* d_out, int out_size, void* d_ws, size_t ws_size,
                              hipStream_t stream)
{
  const float* x  = (const float*)d_in[0];
  const float* wq = (const float*)d_in[1];
  const float* wk = (const float*)d_in[2];
  const float* wv = (const float*)d_in[3];
  const float* wo = (const float*)d_in[4];
  const float* fc = (const float*)d_in[5];
  // d_in[6] = mask: causal triu(-1e9) applied analytically inside attn_kernel.
  float* out = (float*)d_out;

  char* ws = (char*)d_ws;
  __bf16* q_buf    = (__bf16*)(ws);                       //  8 MB [NH][S][HD]
  __bf16* k_buf    = (__bf16*)(ws +  8u * 1024 * 1024);   //  2 MB [NKV][S][HD]
  __bf16* v_buf    = (__bf16*)(ws + 10u * 1024 * 1024);   //  2 MB [NKV][HD][S]
  __bf16* attn_buf = (__bf16*)(ws + 12u * 1024 * 1024);   //  8 MB [S][NH*HD]
  __bf16* xb       = (__bf16*)(ws + 20u * 1024 * 1024);   //  8 MB [S][DIM]
  __bf16* wb       = (__bf16*)(ws + 28u * 1024 * 1024);   // 12 MB [3072][DIM]
  __bf16* wob      = (__bf16*)(ws + 40u * 1024 * 1024);   //  8 MB [DIM][DIM]

  cvt_kernel<<<dim3(14336), 256, 0, stream>>>(x, wq, wk, wv, wo, xb, wb, wob);
  qkv_gemm<<<dim3(24, 16), 256, 0, stream>>>(xb, wb, q_buf, k_buf, v_buf);
  rope_kernel<<<dim3(10240), 256, 0, stream>>>(q_buf, k_buf, fc);
  attn_kernel<<<dim3(32, 32), 256, 0, stream>>>(q_buf, k_buf, v_buf, attn_buf);
  oproj_gemm<<<dim3(16, 16), 256, 0, stream>>>(attn_buf, wob, out);
}

// Round 3
// 356.827 us; speedup vs baseline: 2.1341x; 1.0501x over previous
//
#include <hip/hip_runtime.h>
#include <hip/hip_bf16.h>

#define S_LEN 2048
#define DIM_  2048
#define NH    32
#define NKV   8
#define HD    64
#define SCALE 0.125f   // HD^-0.5

typedef __bf16 bf16x8 __attribute__((ext_vector_type(8)));
typedef __bf16 bf16x4 __attribute__((ext_vector_type(4)));
typedef float  f32x4  __attribute__((ext_vector_type(4)));

#define AS_GLOBAL(p) ((const __attribute__((address_space(1))) void*)(p))
#define AS_LDS(p)    ((__attribute__((address_space(3))) void*)(p))

// ---------------- fp32 -> bf16 conversion (x, wq|wk|wv concat, wo) ----------
__global__ __launch_bounds__(256) void cvt_kernel(
    const float* __restrict__ x,  const float* __restrict__ wq,
    const float* __restrict__ wk, const float* __restrict__ wv,
    const float* __restrict__ wo,
    __bf16* __restrict__ xb, __bf16* __restrict__ wb, __bf16* __restrict__ wob)
{
  size_t i = (size_t)blockIdx.x * 256 + threadIdx.x;
  const float* src; __bf16* dst; size_t off;
  if (i < 1048576)      { src = x;  dst = xb;            off = i; }
  else if (i < 2097152) { src = wq; dst = wb;            off = i - 1048576; }
  else if (i < 2359296) { src = wk; dst = wb + 4194304;  off = i - 2097152; }
  else if (i < 2621440) { src = wv; dst = wb + 5242880;  off = i - 2359296; }
  else                  { src = wo; dst = wob;           off = i - 2621440; }
  float4 f = ((const float4*)src)[off];
  bf16x4 r;
  r[0] = (__bf16)f.x; r[1] = (__bf16)f.y; r[2] = (__bf16)f.z; r[3] = (__bf16)f.w;
  ((bf16x4*)dst)[off] = r;
}

// ---------------- m97-structure GEMM main loop ------------------------------
#define BK 32
#define TILE_ELEMS 4096   // 128*32

__device__ __forceinline__ void stage_tile(
    const __bf16* __restrict__ g, int row0, int k0, int ld,
    __bf16* lds, int wave, int lane)
{
#pragma unroll
  for (int iss = 0; iss < 2; ++iss) {
    int off = (wave * 2 + iss) * 1024 + lane * 16;  // byte offset in 8 KB tile
    int r = off >> 6;          // 64 B per row (32 bf16)
    int c = (off & 63) >> 1;   // bf16 col
    __builtin_amdgcn_global_load_lds(
        AS_GLOBAL(g + (size_t)(row0 + r) * ld + k0 + c),
        AS_LDS(lds + (wave * 2 + iss) * 512),   // wave-uniform base
        16, 0, 0);
  }
}

__device__ __forceinline__ void gemm_mainloop(
    const __bf16* __restrict__ A, const __bf16* __restrict__ B,
    int row0, int col0, int lda, int ldb, int nt,
    __bf16* As, __bf16* Bs, f32x4 acc[4][4])
{
  const int lane = threadIdx.x & 63;
  const int wave = threadIdx.x >> 6;
  const int wr = wave >> 1, wc = wave & 1;
  const int fr = lane & 15, fg = lane >> 4;

  stage_tile(A, row0, 0, lda, As, wave, lane);
  stage_tile(B, col0, 0, ldb, Bs, wave, lane);

  for (int t = 0; t < nt; ++t) {
    const int cur = t & 1;
    if (t + 1 < nt) {
      stage_tile(A, row0, (t + 1) * BK, lda, As + (cur ^ 1) * TILE_ELEMS, wave, lane);
      stage_tile(B, col0, (t + 1) * BK, ldb, Bs + (cur ^ 1) * TILE_ELEMS, wave, lane);
    }
    __syncthreads();
    bf16x8 a[4], b[4];
#pragma unroll
    for (int mi = 0; mi < 4; ++mi)
      a[mi] = *(const bf16x8*)(As + cur * TILE_ELEMS + (wr * 64 + mi * 16 + fr) * 32 + fg * 8);
#pragma unroll
    for (int ni = 0; ni < 4; ++ni)
      b[ni] = *(const bf16x8*)(Bs + cur * TILE_ELEMS + (wc * 64 + ni * 16 + fr) * 32 + fg * 8);
#pragma unroll
    for (int mi = 0; mi < 4; ++mi)
#pragma unroll
      for (int ni = 0; ni < 4; ++ni)
        acc[mi][ni] = __builtin_amdgcn_mfma_f32_16x16x32_bf16(a[mi], b[ni], acc[mi][ni], 0, 0, 0);
    __syncthreads();
  }
}

// ---------------- QKV projection ------------------------------------------
__global__ __launch_bounds__(256) void qkv_gemm(
    const __bf16* __restrict__ xb, const __bf16* __restrict__ wb,
    __bf16* __restrict__ q_buf, __bf16* __restrict__ k_buf, __bf16* __restrict__ v_buf)
{
  __shared__ __bf16 As[2 * TILE_ELEMS];
  __shared__ __bf16 Bs[2 * TILE_ELEMS];
  const int lane = threadIdx.x & 63;
  const int wave = threadIdx.x >> 6;
  const int wr = wave >> 1, wc = wave & 1;
  const int fr = lane & 15, fg = lane >> 4;
  const int row0 = blockIdx.y * 128;
  const int col0 = blockIdx.x * 128;

  f32x4 acc[4][4] = {};
  gemm_mainloop(xb, wb, row0, col0, DIM_, DIM_, DIM_ / BK, As, Bs, acc);

  const int rowg0 = row0 + wr * 64;
  const int colg0 = col0 + wc * 64;
#pragma unroll
  for (int mi = 0; mi < 4; ++mi) {
#pragma unroll
    for (int ni = 0; ni < 4; ++ni) {
#pragma unroll
      for (int j = 0; j < 4; ++j) {
        int row = rowg0 + mi * 16 + fg * 4 + j;
        int col = colg0 + ni * 16 + fr;
        float v = acc[mi][ni][j];
        if (col < 2048) {
          int h = col >> 6, d = col & 63;
          q_buf[((size_t)h * S_LEN + row) * HD + d] = (__bf16)v;
        } else if (col < 2560) {
          int c = col - 2048, g = c >> 6, d = c & 63;
          k_buf[((size_t)g * S_LEN + row) * HD + d] = (__bf16)v;
        } else {
          int c = col - 2560, g = c >> 6, d = c & 63;
          v_buf[((size_t)g * HD + d) * S_LEN + row] = (__bf16)v;  // transposed
        }
      }
    }
  }
}

// ---------------- Output projection: out = attn @ wo^T ----------------------
__global__ __launch_bounds__(256) void oproj_gemm(
    const __bf16* __restrict__ attn_buf, const __bf16* __restrict__ wob,
    float* __restrict__ out)
{
  __shared__ __bf16 As[2 * TILE_ELEMS];
  __shared__ __bf16 Bs[2 * TILE_ELEMS];
  const int lane = threadIdx.x & 63;
  const int wave = threadIdx.x >> 6;
  const int wr = wave >> 1, wc = wave & 1;
  const int fr = lane & 15, fg = lane >> 4;
  const int row0 = blockIdx.y * 128;
  const int col0 = blockIdx.x * 128;

  f32x4 acc[4][4] = {};
  gemm_mainloop(attn_buf, wob, row0, col0, DIM_, DIM_, DIM_ / BK, As, Bs, acc);

  const int rowg0 = row0 + wr * 64;
  const int colg0 = col0 + wc * 64;
#pragma unroll
  for (int mi = 0; mi < 4; ++mi)
#pragma unroll
    for (int ni = 0; ni < 4; ++ni)
#pragma unroll
      for (int j = 0; j < 4; ++j) {
        int row = rowg0 + mi * 16 + fg * 4 + j;
        int col = colg0 + ni * 16 + fr;
        out[(size_t)row * DIM_ + col] = acc[mi][ni][j];
      }
}

// ---------------- RoPE on Q and K (in place, bf16) --------------------------
__global__ __launch_bounds__(256) void rope_kernel(
    __bf16* __restrict__ q_buf, __bf16* __restrict__ k_buf,
    const float* __restrict__ fc)
{
  int idx = blockIdx.x * 256 + threadIdx.x;
  int i    = idx & 31;
  int hs   = idx >> 5;
  int spos = hs & (S_LEN - 1);
  int h    = hs >> 11;
  __bf16* buf = (h < NH) ? (q_buf + ((size_t)h * S_LEN + spos) * HD)
                         : (k_buf + ((size_t)(h - NH) * S_LEN + spos) * HD);
  float c = fc[(spos * 32 + i) * 2 + 0];
  float s = fc[(spos * 32 + i) * 2 + 1];
  float x1 = (float)buf[2 * i], x2 = (float)buf[2 * i + 1];
  buf[2 * i + 0] = (__bf16)(x1 * c - x2 * s);
  buf[2 * i + 1] = (__bf16)(x1 * s + x2 * c);
}

// ---------------- Flash attention (causal, GQA, swapped-QK) -----------------
// Grid: (S/64, NH). Block: 4 waves; wave w owns q-rows [qt*64+w*16, +16).
// Swapped QK^T: S^T = mfma(A=K, B=Q) -> lane holds q-row (lane&15),
// kv = 16c + 4*(lane>>4) + j. Row softmax = in-lane tree + 2 shuffles.
// P -> per-wave LDS slab (no __syncthreads) -> A-frag for PV.
__global__ __launch_bounds__(256) void attn_kernel(
    const __bf16* __restrict__ q_buf, const __bf16* __restrict__ k_buf,
    const __bf16* __restrict__ v_buf, __bf16* __restrict__ attn_buf)
{
  __shared__ __align__(16) __bf16 lds_p[4][16][72];  // row stride 144 B
  const int lane = threadIdx.x & 63;
  const int wave = threadIdx.x >> 6;
  const int qt   = (int)gridDim.x - 1 - (int)blockIdx.x;  // long blocks first
  const int h = blockIdx.y;
  const int g = h >> 2;             // NREP = 4
  const int r0 = qt * 64 + wave * 16;
  const int lrow = lane & 15;
  const int lgrp = lane >> 4;
  const int lk = lgrp * 8;

  const __bf16* qh = q_buf + (size_t)h * S_LEN * HD;
  const __bf16* kh = k_buf + (size_t)g * S_LEN * HD;
  const __bf16* vh = v_buf + (size_t)g * HD * S_LEN;

  bf16x8 qa[2];
#pragma unroll
  for (int kk = 0; kk < 2; ++kk)
    qa[kk] = *(const bf16x8*)(qh + (size_t)(r0 + lrow) * HD + kk * 32 + lk);

  const float KS = 0.125f * 1.44269504088896f;  // scale * log2(e)
  float m_col = -3.0e38f, l_col = 0.f;
  f32x4 oacc[4] = {};

  const int nt = qt + 1;
  for (int t = 0; t < nt; ++t) {
    const int t0 = t * 64;
    const bool lastt = (t == nt - 1);

    // ---- QK^T (swapped): S^T[kv][q] ----
    f32x4 sc[4] = {};
#pragma unroll
    for (int c = 0; c < 4; ++c) {
      if (!lastt || c <= wave) {
#pragma unroll
        for (int kk = 0; kk < 2; ++kk) {
          bf16x8 ka = *(const bf16x8*)(kh + (size_t)(t0 + c * 16 + lrow) * HD + kk * 32 + lk);
          sc[c] = __builtin_amdgcn_mfma_f32_16x16x32_bf16(ka, qa[kk], sc[c], 0, 0, 0);
        }
      }
    }

    // ---- scale + causal mask (log2 domain) ----
    float p[16];
    if (lastt) {
      const int q = r0 + lrow;
#pragma unroll
      for (int c = 0; c < 4; ++c)
#pragma unroll
        for (int j = 0; j < 4; ++j) {
          int kv = t0 + c * 16 + lgrp * 4 + j;
          p[c * 4 + j] = (c <= wave && kv <= q) ? sc[c][j] * KS : -3.0e38f;
        }
    } else {
#pragma unroll
      for (int c = 0; c < 4; ++c)
#pragma unroll
        for (int j = 0; j < 4; ++j)
          p[c * 4 + j] = sc[c][j] * KS;
    }

    // ---- row max: in-lane tree + 2 shuffles ----
    float m8[8], m4[4];
#pragma unroll
    for (int i = 0; i < 8; ++i) m8[i] = fmaxf(p[i], p[i + 8]);
#pragma unroll
    for (int i = 0; i < 4; ++i) m4[i] = fmaxf(m8[i], m8[i + 4]);
    float mx = fmaxf(fmaxf(m4[0], m4[1]), fmaxf(m4[2], m4[3]));
    mx = fmaxf(mx, __shfl_xor(mx, 16, 64));
    mx = fmaxf(mx, __shfl_xor(mx, 32, 64));

    float nm = fmaxf(m_col, mx);
    float alpha = __builtin_amdgcn_exp2f(m_col - nm);
    m_col = nm;

    // ---- exp + row sum ----
#pragma unroll
    for (int i = 0; i < 16; ++i)
      p[i] = __builtin_amdgcn_exp2f(p[i] - nm);
    float s8[8], s4[4];
#pragma unroll
    for (int i = 0; i < 8; ++i) s8[i] = p[i] + p[i + 8];
#pragma unroll
    for (int i = 0; i < 4; ++i) s4[i] = s8[i] + s8[i + 4];
    float rs = (s4[0] + s4[1]) + (s4[2] + s4[3]);
    rs += __shfl_xor(rs, 16, 64);
    rs += __shfl_xor(rs, 32, 64);
    l_col = l_col * alpha + rs;

    // ---- alpha -> O-row layout, rescale O ----
    float ar[4];
#pragma unroll
    for (int j = 0; j < 4; ++j)
      ar[j] = __shfl(alpha, lgrp * 4 + j, 64);
#pragma unroll
    for (int nf = 0; nf < 4; ++nf)
#pragma unroll
      for (int j = 0; j < 4; ++j)
        oacc[nf][j] *= ar[j];

    // ---- P -> LDS (per-wave slab, packed u32, no barrier) ----
#pragma unroll
    for (int c = 0; c < 4; ++c)
#pragma unroll
      for (int e = 0; e < 2; ++e) {
        union { __bf16 hh[2]; unsigned u; } pk;
        pk.hh[0] = (__bf16)p[c * 4 + 2 * e];
        pk.hh[1] = (__bf16)p[c * 4 + 2 * e + 1];
        *(unsigned*)&lds_p[wave][lrow][c * 16 + lgrp * 4 + 2 * e] = pk.u;
      }
    asm volatile("s_waitcnt lgkmcnt(0)" ::: "memory");

    bf16x8 pa0 = *(const bf16x8*)&lds_p[wave][lrow][lk];
#pragma unroll
    for (int nf = 0; nf < 4; ++nf) {
      bf16x8 vb = *(const bf16x8*)(vh + (size_t)(nf * 16 + lrow) * S_LEN + t0 + lk);
      oacc[nf] = __builtin_amdgcn_mfma_f32_16x16x32_bf16(pa0, vb, oacc[nf], 0, 0, 0);
    }
    if (!lastt || wave >= 2) {
      bf16x8 pa1 = *(const bf16x8*)&lds_p[wave][lrow][32 + lk];
#pragma unroll
      for (int nf = 0; nf < 4; ++nf) {
        bf16x8 vb = *(const bf16x8*)(vh + (size_t)(nf * 16 + lrow) * S_LEN + t0 + 32 + lk);
        oacc[nf] = __builtin_amdgcn_mfma_f32_16x16x32_bf16(pa1, vb, oacc[nf], 0, 0, 0);
      }
    }
  }

  // ---- epilogue: divide by row-sum (redistribute to O layout), store ----
  float rlr[4];
#pragma unroll
  for (int j = 0; j < 4; ++j)
    rlr[j] = 1.0f / __shfl(l_col, lgrp * 4 + j, 64);
#pragma unroll
  for (int nf = 0; nf < 4; ++nf)
#pragma unroll
    for (int j = 0; j < 4; ++j) {
      int row = r0 + lgrp * 4 + j;
      attn_buf[(size_t)row * (NH * HD) + h * HD + nf * 16 + lrow] =
          (__bf16)(oacc[nf][j] * rlr[j]);
    }
}

extern "C" void kernel_launch(void* const* d_in, const int* in_sizes, int n_in,
                              void* d_out, int out_size, void* d_ws, size_t ws_size,
                              hipStream_t stream)
{
  const float* x  = (const float*)d_in[0];
  const float* wq = (const float*)d_in[1];
  const float* wk = (const float*)d_in[2];
  const float* wv = (const float*)d_in[3];
  const float* wo = (const float*)d_in[4];
  const float* fc = (const float*)d_in[5];
  float* out = (float*)d_out;

  char* ws = (char*)d_ws;
  __bf16* q_buf    = (__bf16*)(ws);                       //  8 MB [NH][S][HD]
  __bf16* k_buf    = (__bf16*)(ws +  8u * 1024 * 1024);   //  2 MB [NKV][S][HD]
  __bf16* v_buf    = (__bf16*)(ws + 10u * 1024 * 1024);   //  2 MB [NKV][HD][S]
  __bf16* attn_buf = (__bf16*)(ws + 12u * 1024 * 1024);   //  8 MB [S][NH*HD]
  __bf16* xb       = (__bf16*)(ws + 20u * 1024 * 1024);   //  8 MB [S][DIM]
  __bf16* wb       = (__bf16*)(ws + 28u * 1024 * 1024);   // 12 MB [3072][DIM]
  __bf16* wob      = (__bf16*)(ws + 40u * 1024 * 1024);   //  8 MB [DIM][DIM]

  cvt_kernel<<<dim3(14336), 256, 0, stream>>>(x, wq, wk, wv, wo, xb, wb, wob);
  qkv_gemm<<<dim3(24, 16), 256, 0, stream>>>(xb, wb, q_buf, k_buf, v_buf);
  rope_kernel<<<dim3(10240), 256, 0, stream>>>(q_buf, k_buf, fc);
  attn_kernel<<<dim3(32, 32), 256, 0, stream>>>(q_buf, k_buf, v_buf, attn_buf);
  oproj_gemm<<<dim3(16, 16), 256, 0, stream>>>(attn_buf, wob, out);
}

// Round 4
// 198.387 us; speedup vs baseline: 3.8384x; 1.7986x over previous
//
#include <hip/hip_runtime.h>
#include <hip/hip_bf16.h>

#define S_LEN 2048
#define DIM_  2048
#define NH    32
#define NKV   8
#define HD    64

typedef __bf16 bf16x8 __attribute__((ext_vector_type(8)));
typedef __bf16 bf16x4 __attribute__((ext_vector_type(4)));
typedef float  f32x4  __attribute__((ext_vector_type(4)));

#define AS_GLOBAL(p) ((const __attribute__((address_space(1))) void*)(p))
#define AS_LDS(p)    ((__attribute__((address_space(3))) void*)(p))

// ---------------- fp32 -> bf16 conversion (x, wq|wk|wv concat, wo) ----------
__global__ __launch_bounds__(256) void cvt_kernel(
    const float* __restrict__ x,  const float* __restrict__ wq,
    const float* __restrict__ wk, const float* __restrict__ wv,
    const float* __restrict__ wo,
    __bf16* __restrict__ xb, __bf16* __restrict__ wb, __bf16* __restrict__ wob)
{
  size_t i = (size_t)blockIdx.x * 256 + threadIdx.x;
  const float* src; __bf16* dst; size_t off;
  if (i < 1048576)      { src = x;  dst = xb;            off = i; }
  else if (i < 2097152) { src = wq; dst = wb;            off = i - 1048576; }
  else if (i < 2359296) { src = wk; dst = wb + 4194304;  off = i - 2097152; }
  else if (i < 2621440) { src = wv; dst = wb + 5242880;  off = i - 2359296; }
  else                  { src = wo; dst = wob;           off = i - 2621440; }
  float4 f = ((const float4*)src)[off];
  bf16x4 r;
  r[0] = (__bf16)f.x; r[1] = (__bf16)f.y; r[2] = (__bf16)f.z; r[3] = (__bf16)f.w;
  ((bf16x4*)dst)[off] = r;
}

// ---------------- m97-structure GEMM main loop ------------------------------
#define BK 32
#define TILE_ELEMS 4096   // 128*32

__device__ __forceinline__ void stage_tile(
    const __bf16* __restrict__ g, int row0, int k0, int ld,
    __bf16* lds, int wave, int lane)
{
#pragma unroll
  for (int iss = 0; iss < 2; ++iss) {
    int off = (wave * 2 + iss) * 1024 + lane * 16;  // byte offset in 8 KB tile
    int r = off >> 6;          // 64 B per row (32 bf16)
    int c = (off & 63) >> 1;   // bf16 col
    __builtin_amdgcn_global_load_lds(
        AS_GLOBAL(g + (size_t)(row0 + r) * ld + k0 + c),
        AS_LDS(lds + (wave * 2 + iss) * 512),   // wave-uniform base
        16, 0, 0);
  }
}

__device__ __forceinline__ void gemm_mainloop(
    const __bf16* __restrict__ A, const __bf16* __restrict__ B,
    int row0, int col0, int lda, int ldb, int nt,
    __bf16* As, __bf16* Bs, f32x4 acc[4][4])
{
  const int lane = threadIdx.x & 63;
  const int wave = threadIdx.x >> 6;
  const int wr = wave >> 1, wc = wave & 1;
  const int fr = lane & 15, fg = lane >> 4;

  stage_tile(A, row0, 0, lda, As, wave, lane);
  stage_tile(B, col0, 0, ldb, Bs, wave, lane);

  for (int t = 0; t < nt; ++t) {
    const int cur = t & 1;
    if (t + 1 < nt) {
      stage_tile(A, row0, (t + 1) * BK, lda, As + (cur ^ 1) * TILE_ELEMS, wave, lane);
      stage_tile(B, col0, (t + 1) * BK, ldb, Bs + (cur ^ 1) * TILE_ELEMS, wave, lane);
    }
    __syncthreads();
    bf16x8 a[4], b[4];
#pragma unroll
    for (int mi = 0; mi < 4; ++mi)
      a[mi] = *(const bf16x8*)(As + cur * TILE_ELEMS + (wr * 64 + mi * 16 + fr) * 32 + fg * 8);
#pragma unroll
    for (int ni = 0; ni < 4; ++ni)
      b[ni] = *(const bf16x8*)(Bs + cur * TILE_ELEMS + (wc * 64 + ni * 16 + fr) * 32 + fg * 8);
#pragma unroll
    for (int mi = 0; mi < 4; ++mi)
#pragma unroll
      for (int ni = 0; ni < 4; ++ni)
        acc[mi][ni] = __builtin_amdgcn_mfma_f32_16x16x32_bf16(a[mi], b[ni], acc[mi][ni], 0, 0, 0);
    __syncthreads();
  }
}

// ---------------- QKV projection ------------------------------------------
__global__ __launch_bounds__(256) void qkv_gemm(
    const __bf16* __restrict__ xb, const __bf16* __restrict__ wb,
    __bf16* __restrict__ q_buf, __bf16* __restrict__ k_buf, __bf16* __restrict__ v_buf)
{
  __shared__ __bf16 As[2 * TILE_ELEMS];
  __shared__ __bf16 Bs[2 * TILE_ELEMS];
  const int lane = threadIdx.x & 63;
  const int wave = threadIdx.x >> 6;
  const int wr = wave >> 1, wc = wave & 1;
  const int fr = lane & 15, fg = lane >> 4;
  const int row0 = blockIdx.y * 128;
  const int col0 = blockIdx.x * 128;

  f32x4 acc[4][4] = {};
  gemm_mainloop(xb, wb, row0, col0, DIM_, DIM_, DIM_ / BK, As, Bs, acc);

  const int rowg0 = row0 + wr * 64;
  const int colg0 = col0 + wc * 64;
#pragma unroll
  for (int mi = 0; mi < 4; ++mi) {
#pragma unroll
    for (int ni = 0; ni < 4; ++ni) {
#pragma unroll
      for (int j = 0; j < 4; ++j) {
        int row = rowg0 + mi * 16 + fg * 4 + j;
        int col = colg0 + ni * 16 + fr;
        float v = acc[mi][ni][j];
        if (col < 2048) {
          int h = col >> 6, d = col & 63;
          q_buf[((size_t)h * S_LEN + row) * HD + d] = (__bf16)v;
        } else if (col < 2560) {
          int c = col - 2048, g = c >> 6, d = c & 63;
          k_buf[((size_t)g * S_LEN + row) * HD + d] = (__bf16)v;
        } else {
          int c = col - 2560, g = c >> 6, d = c & 63;
          v_buf[((size_t)g * HD + d) * S_LEN + row] = (__bf16)v;  // transposed
        }
      }
    }
  }
}

// ---------------- Output projection: out = attn @ wo^T ----------------------
__global__ __launch_bounds__(256) void oproj_gemm(
    const __bf16* __restrict__ attn_buf, const __bf16* __restrict__ wob,
    float* __restrict__ out)
{
  __shared__ __bf16 As[2 * TILE_ELEMS];
  __shared__ __bf16 Bs[2 * TILE_ELEMS];
  const int lane = threadIdx.x & 63;
  const int wave = threadIdx.x >> 6;
  const int wr = wave >> 1, wc = wave & 1;
  const int fr = lane & 15, fg = lane >> 4;
  const int row0 = blockIdx.y * 128;
  const int col0 = blockIdx.x * 128;

  f32x4 acc[4][4] = {};
  gemm_mainloop(attn_buf, wob, row0, col0, DIM_, DIM_, DIM_ / BK, As, Bs, acc);

  const int rowg0 = row0 + wr * 64;
  const int colg0 = col0 + wc * 64;
#pragma unroll
  for (int mi = 0; mi < 4; ++mi)
#pragma unroll
    for (int ni = 0; ni < 4; ++ni)
#pragma unroll
      for (int j = 0; j < 4; ++j) {
        int row = rowg0 + mi * 16 + fg * 4 + j;
        int col = colg0 + ni * 16 + fr;
        out[(size_t)row * DIM_ + col] = acc[mi][ni][j];
      }
}

// ---------------- RoPE on Q and K (in place, bf16) --------------------------
__global__ __launch_bounds__(256) void rope_kernel(
    __bf16* __restrict__ q_buf, __bf16* __restrict__ k_buf,
    const float* __restrict__ fc)
{
  int idx = blockIdx.x * 256 + threadIdx.x;
  int i    = idx & 31;
  int hs   = idx >> 5;
  int spos = hs & (S_LEN - 1);
  int h    = hs >> 11;
  __bf16* buf = (h < NH) ? (q_buf + ((size_t)h * S_LEN + spos) * HD)
                         : (k_buf + ((size_t)(h - NH) * S_LEN + spos) * HD);
  float c = fc[(spos * 32 + i) * 2 + 0];
  float s = fc[(spos * 32 + i) * 2 + 1];
  float x1 = (float)buf[2 * i], x2 = (float)buf[2 * i + 1];
  buf[2 * i + 0] = (__bf16)(x1 * c - x2 * s);
  buf[2 * i + 1] = (__bf16)(x1 * s + x2 * c);
}

// ---------------- Flash attention (causal, GQA, swapped-QK, shared KV) ------
// Grid: (S/128, NH). Block: 8 waves; wave w owns q-rows [qt*128+w*16, +16).
// K,V tiles (64x64 bf16) double-buffered in LDS, shared by all 8 waves,
// reg-staged (async split: load-early / write-late) with XOR chunk swizzle
// (chunk_col ^= row&7) to kill the stride-128B ds_read_b128 bank conflict.
__global__ __launch_bounds__(512) void attn_kernel(
    const __bf16* __restrict__ q_buf, const __bf16* __restrict__ k_buf,
    const __bf16* __restrict__ v_buf, __bf16* __restrict__ attn_buf)
{
  __shared__ __align__(16) __bf16 Ks[2][64 * 64];   // 2 x 8 KB
  __shared__ __align__(16) __bf16 Vs[2][64 * 64];   // 2 x 8 KB (V^T: [d][kv])
  __shared__ __align__(16) __bf16 lds_p[8][16][72]; // per-wave P slab

  const int tid  = threadIdx.x;
  const int lane = tid & 63;
  const int wave = tid >> 6;
  const int qt = (int)gridDim.x - 1 - (int)blockIdx.x;  // long blocks first
  const int h = blockIdx.y;
  const int g = h >> 2;             // NREP = 4
  const int r0 = qt * 128 + wave * 16;
  const int lrow = lane & 15;
  const int lgrp = lane >> 4;
  const int lk = lgrp * 8;

  const __bf16* qh = q_buf + (size_t)h * S_LEN * HD;
  const __bf16* kh = k_buf + (size_t)g * S_LEN * HD;
  const __bf16* vh = v_buf + (size_t)g * HD * S_LEN;

  // staging assignment: thread -> one 16B chunk of K tile and one of V tile
  const int sr   = tid >> 3;            // row 0..63 (kv row for K, d row for V)
  const int scol = tid & 7;             // source 16B chunk within 128B row
  const int dcol = scol ^ (sr & 7);     // swizzled dest chunk

  bf16x8 qa[2];
#pragma unroll
  for (int kk = 0; kk < 2; ++kk)
    qa[kk] = *(const bf16x8*)(qh + (size_t)(r0 + lrow) * HD + kk * 32 + lk);

  const float KS = 0.125f * 1.44269504088896f;  // scale * log2(e)
  float m_col = -3.0e38f, l_col = 0.f;
  f32x4 oacc[4] = {};

  const int nt = 2 * qt + 2;

  // prologue: stage tile 0 into buffer 0
  {
    uint4 k0 = *(const uint4*)(kh + (size_t)sr * HD + scol * 8);
    uint4 v0 = *(const uint4*)(vh + (size_t)sr * S_LEN + scol * 8);
    *(uint4*)(&Ks[0][sr * 64 + dcol * 8]) = k0;
    *(uint4*)(&Vs[0][sr * 64 + dcol * 8]) = v0;
  }
  __syncthreads();

  for (int t = 0; t < nt; ++t) {
    const int cur = t & 1;
    const int t0 = t * 64;

    // ---- issue next-tile global loads early (clamped; unconditional) ----
    const int tn0 = (t + 1 < nt ? t + 1 : t) * 64;
    uint4 kreg = *(const uint4*)(kh + (size_t)(tn0 + sr) * HD + scol * 8);
    uint4 vreg = *(const uint4*)(vh + (size_t)sr * S_LEN + tn0 + scol * 8);

    const int dmax = r0 + 15 - t0;   // max valid (kv - t0) for this wave
    if (dmax >= 0) {
      // ---- QK^T (swapped): lane holds q-row (lane&15), kv = 16c+4*lgrp+j ----
      f32x4 sc[4] = {};
      const int cmax = dmax >> 4;
#pragma unroll
      for (int c = 0; c < 4; ++c) {
        if (c <= cmax) {
#pragma unroll
          for (int kk = 0; kk < 2; ++kk) {
            bf16x8 ka = *(const bf16x8*)(
                &Ks[cur][(c * 16 + lrow) * 64 + (((kk * 4 + lgrp) ^ (lrow & 7)) * 8)]);
            sc[c] = __builtin_amdgcn_mfma_f32_16x16x32_bf16(ka, qa[kk], sc[c], 0, 0, 0);
          }
        }
      }

      // ---- scale + causal mask (log2 domain) ----
      float p[16];
      const int q = r0 + lrow;
      if (t0 + 63 <= r0) {
#pragma unroll
        for (int c = 0; c < 4; ++c)
#pragma unroll
          for (int j = 0; j < 4; ++j)
            p[c * 4 + j] = sc[c][j] * KS;
      } else {
#pragma unroll
        for (int c = 0; c < 4; ++c)
#pragma unroll
          for (int j = 0; j < 4; ++j) {
            int kv = t0 + c * 16 + lgrp * 4 + j;
            p[c * 4 + j] = (kv <= q) ? sc[c][j] * KS : -3.0e38f;
          }
      }

      // ---- row max: in-lane tree + 2 shuffles ----
      float m8[8], m4[4];
#pragma unroll
      for (int i = 0; i < 8; ++i) m8[i] = fmaxf(p[i], p[i + 8]);
#pragma unroll
      for (int i = 0; i < 4; ++i) m4[i] = fmaxf(m8[i], m8[i + 4]);
      float mx = fmaxf(fmaxf(m4[0], m4[1]), fmaxf(m4[2], m4[3]));
      mx = fmaxf(mx, __shfl_xor(mx, 16, 64));
      mx = fmaxf(mx, __shfl_xor(mx, 32, 64));

      float nm = fmaxf(m_col, mx);
      float alpha = __builtin_amdgcn_exp2f(m_col - nm);
      m_col = nm;

      // ---- exp + row sum ----
#pragma unroll
      for (int i = 0; i < 16; ++i)
        p[i] = __builtin_amdgcn_exp2f(p[i] - nm);
      float s8[8], s4[4];
#pragma unroll
      for (int i = 0; i < 8; ++i) s8[i] = p[i] + p[i + 8];
#pragma unroll
      for (int i = 0; i < 4; ++i) s4[i] = s8[i] + s8[i + 4];
      float rs = (s4[0] + s4[1]) + (s4[2] + s4[3]);
      rs += __shfl_xor(rs, 16, 64);
      rs += __shfl_xor(rs, 32, 64);
      l_col = l_col * alpha + rs;

      // ---- alpha -> O-row layout, rescale O ----
      float ar[4];
#pragma unroll
      for (int j = 0; j < 4; ++j)
        ar[j] = __shfl(alpha, lgrp * 4 + j, 64);
#pragma unroll
      for (int nf = 0; nf < 4; ++nf)
#pragma unroll
        for (int j = 0; j < 4; ++j)
          oacc[nf][j] *= ar[j];

      // ---- P -> per-wave LDS slab (packed u32, in-wave, no barrier) ----
#pragma unroll
      for (int c = 0; c < 4; ++c)
#pragma unroll
        for (int e = 0; e < 2; ++e) {
          union { __bf16 hh[2]; unsigned u; } pk;
          pk.hh[0] = (__bf16)p[c * 4 + 2 * e];
          pk.hh[1] = (__bf16)p[c * 4 + 2 * e + 1];
          *(unsigned*)&lds_p[wave][lrow][c * 16 + lgrp * 4 + 2 * e] = pk.u;
        }
      asm volatile("s_waitcnt lgkmcnt(0)" ::: "memory");

      // ---- PV: O^T-frag = P-frag x V-frag, V from swizzled LDS ----
      bf16x8 pa0 = *(const bf16x8*)&lds_p[wave][lrow][lk];
#pragma unroll
      for (int nf = 0; nf < 4; ++nf) {
        bf16x8 vb = *(const bf16x8*)(
            &Vs[cur][(nf * 16 + lrow) * 64 + ((lgrp ^ (lrow & 7)) * 8)]);
        oacc[nf] = __builtin_amdgcn_mfma_f32_16x16x32_bf16(pa0, vb, oacc[nf], 0, 0, 0);
      }
      if (dmax >= 32) {
        bf16x8 pa1 = *(const bf16x8*)&lds_p[wave][lrow][32 + lk];
#pragma unroll
        for (int nf = 0; nf < 4; ++nf) {
          bf16x8 vb = *(const bf16x8*)(
              &Vs[cur][(nf * 16 + lrow) * 64 + (((4 + lgrp) ^ (lrow & 7)) * 8)]);
          oacc[nf] = __builtin_amdgcn_mfma_f32_16x16x32_bf16(pa1, vb, oacc[nf], 0, 0, 0);
        }
      }
    }

    // ---- write-late: next tile regs -> back buffer ----
    *(uint4*)(&Ks[cur ^ 1][sr * 64 + dcol * 8]) = kreg;
    *(uint4*)(&Vs[cur ^ 1][sr * 64 + dcol * 8]) = vreg;
    __syncthreads();
  }

  // ---- epilogue: divide by row-sum (redistribute to O layout), store ----
  float rlr[4];
#pragma unroll
  for (int j = 0; j < 4; ++j)
    rlr[j] = 1.0f / __shfl(l_col, lgrp * 4 + j, 64);
#pragma unroll
  for (int nf = 0; nf < 4; ++nf)
#pragma unroll
    for (int j = 0; j < 4; ++j) {
      int row = r0 + lgrp * 4 + j;
      attn_buf[(size_t)row * (NH * HD) + h * HD + nf * 16 + lrow] =
          (__bf16)(oacc[nf][j] * rlr[j]);
    }
}

extern "C" void kernel_launch(void* const* d_in, const int* in_sizes, int n_in,
                              void* d_out, int out_size, void* d_ws, size_t ws_size,
                              hipStream_t stream)
{
  const float* x  = (const float*)d_in[0];
  const float* wq = (const float*)d_in[1];
  const float* wk = (const float*)d_in[2];
  const float* wv = (const float*)d_in[3];
  const float* wo = (const float*)d_in[4];
  const float* fc = (const float*)d_in[5];
  float* out = (float*)d_out;

  char* ws = (char*)d_ws;
  __bf16* q_buf    = (__bf16*)(ws);                       //  8 MB [NH][S][HD]
  __bf16* k_buf    = (__bf16*)(ws +  8u * 1024 * 1024);   //  2 MB [NKV][S][HD]
  __bf16* v_buf    = (__bf16*)(ws + 10u * 1024 * 1024);   //  2 MB [NKV][HD][S]
  __bf16* attn_buf = (__bf16*)(ws + 12u * 1024 * 1024);   //  8 MB [S][NH*HD]
  __bf16* xb       = (__bf16*)(ws + 20u * 1024 * 1024);   //  8 MB [S][DIM]
  __bf16* wb       = (__bf16*)(ws + 28u * 1024 * 1024);   // 12 MB [3072][DIM]
  __bf16* wob      = (__bf16*)(ws + 40u * 1024 * 1024);   //  8 MB [DIM][DIM]

  cvt_kernel<<<dim3(14336), 256, 0, stream>>>(x, wq, wk, wv, wo, xb, wb, wob);
  qkv_gemm<<<dim3(24, 16), 256, 0, stream>>>(xb, wb, q_buf, k_buf, v_buf);
  rope_kernel<<<dim3(10240), 256, 0, stream>>>(q_buf, k_buf, fc);
  attn_kernel<<<dim3(16, 32), 512, 0, stream>>>(q_buf, k_buf, v_buf, attn_buf);
  oproj_gemm<<<dim3(16, 16), 256, 0, stream>>>(attn_buf, wob, out);
}

// Round 5
// 173.405 us; speedup vs baseline: 4.3914x; 1.1441x over previous
//
#include <hip/hip_runtime.h>
#include <hip/hip_bf16.h>

#define S_LEN 2048
#define DIM_  2048
#define NH    32
#define NKV   8
#define HD    64

typedef __bf16 bf16x8 __attribute__((ext_vector_type(8)));
typedef __bf16 bf16x4 __attribute__((ext_vector_type(4)));
typedef float  f32x4  __attribute__((ext_vector_type(4)));

#define AS_GLOBAL(p) ((const __attribute__((address_space(1))) void*)(p))
#define AS_LDS(p)    ((__attribute__((address_space(3))) void*)(p))

// ---------------- fp32 -> bf16 conversion (x, wq|wk|wv concat, wo) ----------
__global__ __launch_bounds__(256) void cvt_kernel(
    const float* __restrict__ x,  const float* __restrict__ wq,
    const float* __restrict__ wk, const float* __restrict__ wv,
    const float* __restrict__ wo,
    __bf16* __restrict__ xb, __bf16* __restrict__ wb, __bf16* __restrict__ wob)
{
  size_t i = (size_t)blockIdx.x * 256 + threadIdx.x;
  const float* src; __bf16* dst; size_t off;
  if (i < 1048576)      { src = x;  dst = xb;            off = i; }
  else if (i < 2097152) { src = wq; dst = wb;            off = i - 1048576; }
  else if (i < 2359296) { src = wk; dst = wb + 4194304;  off = i - 2097152; }
  else if (i < 2621440) { src = wv; dst = wb + 5242880;  off = i - 2359296; }
  else                  { src = wo; dst = wob;           off = i - 2621440; }
  float4 f = ((const float4*)src)[off];
  bf16x4 r;
  r[0] = (__bf16)f.x; r[1] = (__bf16)f.y; r[2] = (__bf16)f.z; r[3] = (__bf16)f.w;
  ((bf16x4*)dst)[off] = r;
}

// ---------------- 128x128 GEMM, 8 waves (wave = 64x32 out) ------------------
// Latency-tolerant variant of the m97 structure: 512 thr = 8 waves (2x4),
// double resident waves vs 4-wave at the same 32 KB LDS footprint.
#define BK 32
#define TILE_ELEMS 4096   // 128*32

// 512 threads stage one 128x32 bf16 tile (8 KB): one 16B chunk each.
__device__ __forceinline__ void stage_tile(
    const __bf16* __restrict__ g, int row0, int k0, int ld, __bf16* lds)
{
  const int tid = threadIdx.x;
  int off = tid * 16;        // byte offset in 8 KB tile
  int r = off >> 6;          // 64 B per row (32 bf16)
  int c = (off & 63) >> 1;   // bf16 col
  __builtin_amdgcn_global_load_lds(
      AS_GLOBAL(g + (size_t)(row0 + r) * ld + k0 + c),
      AS_LDS(lds + (tid >> 6) * 512),   // wave-uniform base + lane*16
      16, 0, 0);
}

__device__ __forceinline__ void gemm_mainloop(
    const __bf16* __restrict__ A, const __bf16* __restrict__ B,
    int row0, int col0, int lda, int ldb, int nt,
    __bf16* As, __bf16* Bs, f32x4 acc[4][2])
{
  const int lane = threadIdx.x & 63;
  const int wave = threadIdx.x >> 6;
  const int wr = wave >> 2, wc = wave & 3;   // 2x4 wave grid
  const int fr = lane & 15, fg = lane >> 4;

  stage_tile(A, row0, 0, lda, As);
  stage_tile(B, col0, 0, ldb, Bs);

  for (int t = 0; t < nt; ++t) {
    const int cur = t & 1;
    if (t + 1 < nt) {
      stage_tile(A, row0, (t + 1) * BK, lda, As + (cur ^ 1) * TILE_ELEMS);
      stage_tile(B, col0, (t + 1) * BK, ldb, Bs + (cur ^ 1) * TILE_ELEMS);
    }
    __syncthreads();
    bf16x8 a[4], b[2];
#pragma unroll
    for (int mi = 0; mi < 4; ++mi)
      a[mi] = *(const bf16x8*)(As + cur * TILE_ELEMS + (wr * 64 + mi * 16 + fr) * 32 + fg * 8);
#pragma unroll
    for (int ni = 0; ni < 2; ++ni)
      b[ni] = *(const bf16x8*)(Bs + cur * TILE_ELEMS + (wc * 32 + ni * 16 + fr) * 32 + fg * 8);
#pragma unroll
    for (int mi = 0; mi < 4; ++mi)
#pragma unroll
      for (int ni = 0; ni < 2; ++ni)
        acc[mi][ni] = __builtin_amdgcn_mfma_f32_16x16x32_bf16(a[mi], b[ni], acc[mi][ni], 0, 0, 0);
    __syncthreads();
  }
}

// ---------------- QKV projection ------------------------------------------
__global__ __launch_bounds__(512) void qkv_gemm(
    const __bf16* __restrict__ xb, const __bf16* __restrict__ wb,
    __bf16* __restrict__ q_buf, __bf16* __restrict__ k_buf, __bf16* __restrict__ v_buf)
{
  __shared__ __bf16 As[2 * TILE_ELEMS];
  __shared__ __bf16 Bs[2 * TILE_ELEMS];
  const int lane = threadIdx.x & 63;
  const int wave = threadIdx.x >> 6;
  const int wr = wave >> 2, wc = wave & 3;
  const int fr = lane & 15, fg = lane >> 4;
  const int row0 = blockIdx.y * 128;
  const int col0 = blockIdx.x * 128;

  f32x4 acc[4][2] = {};
  gemm_mainloop(xb, wb, row0, col0, DIM_, DIM_, DIM_ / BK, As, Bs, acc);

  const int rowg0 = row0 + wr * 64;
  const int colg0 = col0 + wc * 32;
#pragma unroll
  for (int mi = 0; mi < 4; ++mi) {
#pragma unroll
    for (int ni = 0; ni < 2; ++ni) {
#pragma unroll
      for (int j = 0; j < 4; ++j) {
        int row = rowg0 + mi * 16 + fg * 4 + j;
        int col = colg0 + ni * 16 + fr;
        float v = acc[mi][ni][j];
        if (col < 2048) {
          int h = col >> 6, d = col & 63;
          q_buf[((size_t)h * S_LEN + row) * HD + d] = (__bf16)v;
        } else if (col < 2560) {
          int c = col - 2048, g = c >> 6, d = c & 63;
          k_buf[((size_t)g * S_LEN + row) * HD + d] = (__bf16)v;
        } else {
          int c = col - 2560, g = c >> 6, d = c & 63;
          v_buf[((size_t)g * HD + d) * S_LEN + row] = (__bf16)v;  // transposed
        }
      }
    }
  }
}

// ---------------- Output projection: out = attn @ wo^T ----------------------
__global__ __launch_bounds__(512) void oproj_gemm(
    const __bf16* __restrict__ attn_buf, const __bf16* __restrict__ wob,
    float* __restrict__ out)
{
  __shared__ __bf16 As[2 * TILE_ELEMS];
  __shared__ __bf16 Bs[2 * TILE_ELEMS];
  const int lane = threadIdx.x & 63;
  const int wave = threadIdx.x >> 6;
  const int wr = wave >> 2, wc = wave & 3;
  const int fr = lane & 15, fg = lane >> 4;
  const int row0 = blockIdx.y * 128;
  const int col0 = blockIdx.x * 128;

  f32x4 acc[4][2] = {};
  gemm_mainloop(attn_buf, wob, row0, col0, DIM_, DIM_, DIM_ / BK, As, Bs, acc);

  const int rowg0 = row0 + wr * 64;
  const int colg0 = col0 + wc * 32;
#pragma unroll
  for (int mi = 0; mi < 4; ++mi)
#pragma unroll
    for (int ni = 0; ni < 2; ++ni)
#pragma unroll
      for (int j = 0; j < 4; ++j) {
        int row = rowg0 + mi * 16 + fg * 4 + j;
        int col = colg0 + ni * 16 + fr;
        out[(size_t)row * DIM_ + col] = acc[mi][ni][j];
      }
}

// ---------------- RoPE on Q and K (in place, bf16) --------------------------
__global__ __launch_bounds__(256) void rope_kernel(
    __bf16* __restrict__ q_buf, __bf16* __restrict__ k_buf,
    const float* __restrict__ fc)
{
  int idx = blockIdx.x * 256 + threadIdx.x;
  int i    = idx & 31;
  int hs   = idx >> 5;
  int spos = hs & (S_LEN - 1);
  int h    = hs >> 11;
  __bf16* buf = (h < NH) ? (q_buf + ((size_t)h * S_LEN + spos) * HD)
                         : (k_buf + ((size_t)(h - NH) * S_LEN + spos) * HD);
  float c = fc[(spos * 32 + i) * 2 + 0];
  float s = fc[(spos * 32 + i) * 2 + 1];
  float x1 = (float)buf[2 * i], x2 = (float)buf[2 * i + 1];
  buf[2 * i + 0] = (__bf16)(x1 * c - x2 * s);
  buf[2 * i + 1] = (__bf16)(x1 * s + x2 * c);
}

// ---------------- Flash attention (causal, GQA, swapped-QK, shared KV) ------
// Grid: (S/128, NH). Block: 8 waves; wave w owns q-rows [qt*128+w*16, +16).
// K,V tiles (64x64 bf16) double-buffered in LDS, shared by all 8 waves,
// reg-staged (async split: load-early / write-late) with XOR chunk swizzle.
// Adds: T5 setprio around MFMA clusters, T13 defer-max (THR=8 in log2).
__global__ __launch_bounds__(512) void attn_kernel(
    const __bf16* __restrict__ q_buf, const __bf16* __restrict__ k_buf,
    const __bf16* __restrict__ v_buf, __bf16* __restrict__ attn_buf)
{
  __shared__ __align__(16) __bf16 Ks[2][64 * 64];   // 2 x 8 KB
  __shared__ __align__(16) __bf16 Vs[2][64 * 64];   // 2 x 8 KB (V^T: [d][kv])
  __shared__ __align__(16) __bf16 lds_p[8][16][72]; // per-wave P slab

  const int tid  = threadIdx.x;
  const int lane = tid & 63;
  const int wave = tid >> 6;
  const int qt = (int)gridDim.x - 1 - (int)blockIdx.x;  // long blocks first
  const int h = blockIdx.y;
  const int g = h >> 2;             // NREP = 4
  const int r0 = qt * 128 + wave * 16;
  const int lrow = lane & 15;
  const int lgrp = lane >> 4;
  const int lk = lgrp * 8;

  const __bf16* qh = q_buf + (size_t)h * S_LEN * HD;
  const __bf16* kh = k_buf + (size_t)g * S_LEN * HD;
  const __bf16* vh = v_buf + (size_t)g * HD * S_LEN;

  // staging assignment: thread -> one 16B chunk of K tile and one of V tile
  const int sr   = tid >> 3;            // row 0..63 (kv row for K, d row for V)
  const int scol = tid & 7;             // source 16B chunk within 128B row
  const int dcol = scol ^ (sr & 7);     // swizzled dest chunk

  bf16x8 qa[2];
#pragma unroll
  for (int kk = 0; kk < 2; ++kk)
    qa[kk] = *(const bf16x8*)(qh + (size_t)(r0 + lrow) * HD + kk * 32 + lk);

  const float KS = 0.125f * 1.44269504088896f;  // scale * log2(e)
  float m_col = -3.0e38f, l_col = 0.f;
  f32x4 oacc[4] = {};

  const int nt = 2 * qt + 2;

  // prologue: stage tile 0 into buffer 0
  {
    uint4 k0 = *(const uint4*)(kh + (size_t)sr * HD + scol * 8);
    uint4 v0 = *(const uint4*)(vh + (size_t)sr * S_LEN + scol * 8);
    *(uint4*)(&Ks[0][sr * 64 + dcol * 8]) = k0;
    *(uint4*)(&Vs[0][sr * 64 + dcol * 8]) = v0;
  }
  __syncthreads();

  for (int t = 0; t < nt; ++t) {
    const int cur = t & 1;
    const int t0 = t * 64;

    // ---- issue next-tile global loads early (clamped; unconditional) ----
    const int tn0 = (t + 1 < nt ? t + 1 : t) * 64;
    uint4 kreg = *(const uint4*)(kh + (size_t)(tn0 + sr) * HD + scol * 8);
    uint4 vreg = *(const uint4*)(vh + (size_t)sr * S_LEN + tn0 + scol * 8);

    const int dmax = r0 + 15 - t0;   // max valid (kv - t0) for this wave
    if (dmax >= 0) {
      // ---- QK^T (swapped): lane holds q-row (lane&15), kv = 16c+4*lgrp+j ----
      f32x4 sc[4] = {};
      const int cmax = dmax >> 4;
      __builtin_amdgcn_s_setprio(1);
#pragma unroll
      for (int c = 0; c < 4; ++c) {
        if (c <= cmax) {
#pragma unroll
          for (int kk = 0; kk < 2; ++kk) {
            bf16x8 ka = *(const bf16x8*)(
                &Ks[cur][(c * 16 + lrow) * 64 + (((kk * 4 + lgrp) ^ (lrow & 7)) * 8)]);
            sc[c] = __builtin_amdgcn_mfma_f32_16x16x32_bf16(ka, qa[kk], sc[c], 0, 0, 0);
          }
        }
      }
      __builtin_amdgcn_s_setprio(0);

      // ---- scale + causal mask (log2 domain) ----
      float p[16];
      const int q = r0 + lrow;
      if (t0 + 63 <= r0) {
#pragma unroll
        for (int c = 0; c < 4; ++c)
#pragma unroll
          for (int j = 0; j < 4; ++j)
            p[c * 4 + j] = sc[c][j] * KS;
      } else {
#pragma unroll
        for (int c = 0; c < 4; ++c)
#pragma unroll
          for (int j = 0; j < 4; ++j) {
            int kv = t0 + c * 16 + lgrp * 4 + j;
            p[c * 4 + j] = (kv <= q) ? sc[c][j] * KS : -3.0e38f;
          }
      }

      // ---- row max: in-lane tree + 2 shuffles ----
      float m8[8], m4[4];
#pragma unroll
      for (int i = 0; i < 8; ++i) m8[i] = fmaxf(p[i], p[i + 8]);
#pragma unroll
      for (int i = 0; i < 4; ++i) m4[i] = fmaxf(m8[i], m8[i + 4]);
      float mx = fmaxf(fmaxf(m4[0], m4[1]), fmaxf(m4[2], m4[3]));
      mx = fmaxf(mx, __shfl_xor(mx, 16, 64));
      mx = fmaxf(mx, __shfl_xor(mx, 32, 64));

      // ---- T13 defer-max: skip rescale while max growth <= 8 (log2) ----
      if (__all(mx <= m_col + 8.f)) {
        // keep old m_col; P bounded by 2^8, alpha == 1
      } else {
        float nm = fmaxf(m_col, mx);
        float alpha = __builtin_amdgcn_exp2f(m_col - nm);
        m_col = nm;
        float ar[4];
#pragma unroll
        for (int j = 0; j < 4; ++j)
          ar[j] = __shfl(alpha, lgrp * 4 + j, 64);
#pragma unroll
        for (int nf = 0; nf < 4; ++nf)
#pragma unroll
          for (int j = 0; j < 4; ++j)
            oacc[nf][j] *= ar[j];
        l_col *= alpha;
      }

      // ---- exp + row sum ----
#pragma unroll
      for (int i = 0; i < 16; ++i)
        p[i] = __builtin_amdgcn_exp2f(p[i] - m_col);
      float s8[8], s4[4];
#pragma unroll
      for (int i = 0; i < 8; ++i) s8[i] = p[i] + p[i + 8];
#pragma unroll
      for (int i = 0; i < 4; ++i) s4[i] = s8[i] + s8[i + 4];
      float rs = (s4[0] + s4[1]) + (s4[2] + s4[3]);
      rs += __shfl_xor(rs, 16, 64);
      rs += __shfl_xor(rs, 32, 64);
      l_col += rs;

      // ---- P -> per-wave LDS slab (packed u32, in-wave, no barrier) ----
#pragma unroll
      for (int c = 0; c < 4; ++c)
#pragma unroll
        for (int e = 0; e < 2; ++e) {
          union { __bf16 hh[2]; unsigned u; } pk;
          pk.hh[0] = (__bf16)p[c * 4 + 2 * e];
          pk.hh[1] = (__bf16)p[c * 4 + 2 * e + 1];
          *(unsigned*)&lds_p[wave][lrow][c * 16 + lgrp * 4 + 2 * e] = pk.u;
        }
      asm volatile("s_waitcnt lgkmcnt(0)" ::: "memory");

      // ---- PV: O^T-frag = P-frag x V-frag, V from swizzled LDS ----
      bf16x8 pa0 = *(const bf16x8*)&lds_p[wave][lrow][lk];
      __builtin_amdgcn_s_setprio(1);
#pragma unroll
      for (int nf = 0; nf < 4; ++nf) {
        bf16x8 vb = *(const bf16x8*)(
            &Vs[cur][(nf * 16 + lrow) * 64 + ((lgrp ^ (lrow & 7)) * 8)]);
        oacc[nf] = __builtin_amdgcn_mfma_f32_16x16x32_bf16(pa0, vb, oacc[nf], 0, 0, 0);
      }
      __builtin_amdgcn_s_setprio(0);
      if (dmax >= 32) {
        bf16x8 pa1 = *(const bf16x8*)&lds_p[wave][lrow][32 + lk];
        __builtin_amdgcn_s_setprio(1);
#pragma unroll
        for (int nf = 0; nf < 4; ++nf) {
          bf16x8 vb = *(const bf16x8*)(
              &Vs[cur][(nf * 16 + lrow) * 64 + (((4 + lgrp) ^ (lrow & 7)) * 8)]);
          oacc[nf] = __builtin_amdgcn_mfma_f32_16x16x32_bf16(pa1, vb, oacc[nf], 0, 0, 0);
        }
        __builtin_amdgcn_s_setprio(0);
      }
    }

    // ---- write-late: next tile regs -> back buffer ----
    *(uint4*)(&Ks[cur ^ 1][sr * 64 + dcol * 8]) = kreg;
    *(uint4*)(&Vs[cur ^ 1][sr * 64 + dcol * 8]) = vreg;
    __syncthreads();
  }

  // ---- epilogue: divide by row-sum (redistribute to O layout), store ----
  float rlr[4];
#pragma unroll
  for (int j = 0; j < 4; ++j)
    rlr[j] = 1.0f / __shfl(l_col, lgrp * 4 + j, 64);
#pragma unroll
  for (int nf = 0; nf < 4; ++nf)
#pragma unroll
    for (int j = 0; j < 4; ++j) {
      int row = r0 + lgrp * 4 + j;
      attn_buf[(size_t)row * (NH * HD) + h * HD + nf * 16 + lrow] =
          (__bf16)(oacc[nf][j] * rlr[j]);
    }
}

extern "C" void kernel_launch(void* const* d_in, const int* in_sizes, int n_in,
                              void* d_out, int out_size, void* d_ws, size_t ws_size,
                              hipStream_t stream)
{
  const float* x  = (const float*)d_in[0];
  const float* wq = (const float*)d_in[1];
  const float* wk = (const float*)d_in[2];
  const float* wv = (const float*)d_in[3];
  const float* wo = (const float*)d_in[4];
  const float* fc = (const float*)d_in[5];
  float* out = (float*)d_out;

  char* ws = (char*)d_ws;
  __bf16* q_buf    = (__bf16*)(ws);                       //  8 MB [NH][S][HD]
  __bf16* k_buf    = (__bf16*)(ws +  8u * 1024 * 1024);   //  2 MB [NKV][S][HD]
  __bf16* v_buf    = (__bf16*)(ws + 10u * 1024 * 1024);   //  2 MB [NKV][HD][S]
  __bf16* attn_buf = (__bf16*)(ws + 12u * 1024 * 1024);   //  8 MB [S][NH*HD]
  __bf16* xb       = (__bf16*)(ws + 20u * 1024 * 1024);   //  8 MB [S][DIM]
  __bf16* wb       = (__bf16*)(ws + 28u * 1024 * 1024);   // 12 MB [3072][DIM]
  __bf16* wob      = (__bf16*)(ws + 40u * 1024 * 1024);   //  8 MB [DIM][DIM]

  cvt_kernel<<<dim3(14336), 256, 0, stream>>>(x, wq, wk, wv, wo, xb, wb, wob);
  qkv_gemm<<<dim3(24, 16), 512, 0, stream>>>(xb, wb, q_buf, k_buf, v_buf);
  rope_kernel<<<dim3(10240), 256, 0, stream>>>(q_buf, k_buf, fc);
  attn_kernel<<<dim3(16, 32), 512, 0, stream>>>(q_buf, k_buf, v_buf, attn_buf);
  oproj_gemm<<<dim3(16, 16), 512, 0, stream>>>(attn_buf, wob, out);
}